// Round 1
// baseline (1123.780 us; speedup 1.0000x reference)
//
#include <hip/hip_runtime.h>
#include <math.h>

#define NB      65536
#define LIN     274
#define SEQ     18
#define DM      16
#define NH      4
#define HID     64
#define NLAYER  4
#define EPSF    1e-5f

#define EPB      14              // elements (batch items) per block
#define NTHREADS (EPB * SEQ)     // 252 threads
#define KV_STRIDE 580            // floats per element in kv LDS (2*288 padded; 580%32=4 -> bank-spread, 16B aligned)

__global__ __launch_bounds__(NTHREADS) void ae_fwd(
    const float* __restrict__ x,
    const float* __restrict__ patch_w, const float* __restrict__ patch_b,
    const float* __restrict__ pos_embed,
    const float* __restrict__ ln1_g, const float* __restrict__ ln1_b,
    const float* __restrict__ qkv_w, const float* __restrict__ qkv_b,
    const float* __restrict__ out_w, const float* __restrict__ out_b,
    const float* __restrict__ ln2_g, const float* __restrict__ ln2_b,
    const float* __restrict__ mlp_w1, const float* __restrict__ mlp_b1,
    const float* __restrict__ mlp_w2, const float* __restrict__ mlp_b2,
    const float* __restrict__ lnf_g, const float* __restrict__ lnf_b,
    const float* __restrict__ dec_w, const float* __restrict__ dec_b,
    float* __restrict__ out_y, float* __restrict__ out_z)
{
    __shared__ float s_kv[EPB * KV_STRIDE];   // 32480 B; aliased as x-staging first

    const int tid = threadIdx.x;
    const int e   = tid / SEQ;
    const int s   = tid - e * SEQ;
    const long long b = (long long)blockIdx.x * EPB + e;
    const bool valid = (b < NB);

    // ---- stage x into LDS, fully coalesced (block's elements are contiguous in x) ----
    {
        const long long base = (long long)blockIdx.x * (EPB * LIN);
        const long long lim  = (long long)NB * LIN - 1;
        for (int i = tid; i < EPB * LIN; i += NTHREADS) {
            long long gi = base + i;
            if (gi > lim) gi = lim;               // tail-block clamp (no OOB)
            s_kv[i] = x[gi];
        }
    }
    __syncthreads();

    // ---- patchify: h[s,d] = sum_k x[s*16-7+k] * pw[d,k] + pb[d] + pos[s,d] ----
    float xv[16];
    {
        const float* xe = &s_kv[e * LIN];
        #pragma unroll
        for (int k = 0; k < 16; ++k) {
            int idx = s * 16 - 7 + k;
            xv[k] = (idx >= 0 && idx < LIN) ? xe[idx] : 0.0f;
        }
    }
    float h[DM];
    #pragma unroll
    for (int d = 0; d < DM; ++d) {
        float acc = patch_b[d] + pos_embed[s * DM + d];
        #pragma unroll
        for (int k = 0; k < 16; ++k) acc += xv[k] * patch_w[d * 16 + k];
        h[d] = acc;
    }

    // ---- transformer layers (loop kept rolled: I$ budget) ----
    #pragma unroll 1
    for (int li = 0; li < NLAYER; ++li) {
        // LN1
        float xn[DM];
        {
            float m = 0.f;
            #pragma unroll
            for (int d = 0; d < DM; ++d) m += h[d];
            m *= (1.0f / DM);
            float v = 0.f;
            #pragma unroll
            for (int d = 0; d < DM; ++d) { float t = h[d] - m; v += t * t; }
            v *= (1.0f / DM);
            float inv = rsqrtf(v + EPSF);
            const float* g = ln1_g + li * DM;
            const float* bb = ln1_b + li * DM;
            #pragma unroll
            for (int d = 0; d < DM; ++d) xn[d] = (h[d] - m) * inv * g[d] + bb[d];
        }

        // qkv: row s of xn (local) times W^T rows (uniform -> scalar loads)
        float q[DM], kk[DM], vv[DM];
        {
            const float* W  = qkv_w + li * (3 * DM) * DM;
            const float* Wb = qkv_b + li * (3 * DM);
            #pragma unroll
            for (int j = 0; j < DM; ++j) {
                float aq = Wb[j], ak = Wb[DM + j], av = Wb[2 * DM + j];
                #pragma unroll
                for (int d = 0; d < DM; ++d) {
                    float xd = xn[d];
                    aq += xd * W[(j) * DM + d];
                    ak += xd * W[(DM + j) * DM + d];
                    av += xd * W[(2 * DM + j) * DM + d];
                }
                q[j] = aq; kk[j] = ak; vv[j] = av;
            }
        }

        // publish k,v rows to LDS
        __syncthreads();   // prior LDS reads (x in layer 0 / attn in layer li-1) done
        {
            float* kb = &s_kv[e * KV_STRIDE];
            float* vb = kb + SEQ * DM;
            #pragma unroll
            for (int j = 0; j < DM; ++j) kb[s * DM + j] = kk[j];
            #pragma unroll
            for (int j = 0; j < DM; ++j) vb[s * DM + j] = vv[j];
        }
        __syncthreads();

        // attention (per head: scores, softmax, weighted V) — all reads broadcast within element
        float o[DM];
        {
            const float* kb = &s_kv[e * KV_STRIDE];
            const float* vb = kb + SEQ * DM;
            #pragma unroll
            for (int hh = 0; hh < NH; ++hh) {
                const float q0 = q[hh * 4], q1 = q[hh * 4 + 1], q2 = q[hh * 4 + 2], q3 = q[hh * 4 + 3];
                float sc[SEQ];
                float mx = -1e30f;
                #pragma unroll
                for (int j = 0; j < SEQ; ++j) {
                    const float4 kj = *(const float4*)(kb + j * DM + hh * 4);
                    float t = (q0 * kj.x + q1 * kj.y + q2 * kj.z + q3 * kj.w) * 0.5f;
                    sc[j] = t;
                    mx = fmaxf(mx, t);
                }
                float ssum = 0.f;
                #pragma unroll
                for (int j = 0; j < SEQ; ++j) { float t = __expf(sc[j] - mx); sc[j] = t; ssum += t; }
                const float inv = 1.0f / ssum;
                float a0 = 0.f, a1 = 0.f, a2 = 0.f, a3 = 0.f;
                #pragma unroll
                for (int j = 0; j < SEQ; ++j) {
                    const float4 vj = *(const float4*)(vb + j * DM + hh * 4);
                    const float w = sc[j] * inv;
                    a0 += w * vj.x; a1 += w * vj.y; a2 += w * vj.z; a3 += w * vj.w;
                }
                o[hh * 4] = a0; o[hh * 4 + 1] = a1; o[hh * 4 + 2] = a2; o[hh * 4 + 3] = a3;
            }
        }

        // out projection + residual
        {
            const float* W  = out_w + li * DM * DM;
            const float* Wb = out_b + li * DM;
            #pragma unroll
            for (int d = 0; d < DM; ++d) {
                float acc = Wb[d];
                #pragma unroll
                for (int d2 = 0; d2 < DM; ++d2) acc += o[d2] * W[d * DM + d2];
                h[d] += acc;
            }
        }

        // LN2
        float xn2[DM];
        {
            float m = 0.f;
            #pragma unroll
            for (int d = 0; d < DM; ++d) m += h[d];
            m *= (1.0f / DM);
            float v = 0.f;
            #pragma unroll
            for (int d = 0; d < DM; ++d) { float t = h[d] - m; v += t * t; }
            v *= (1.0f / DM);
            float inv = rsqrtf(v + EPSF);
            const float* g = ln2_g + li * DM;
            const float* bb = ln2_b + li * DM;
            #pragma unroll
            for (int d = 0; d < DM; ++d) xn2[d] = (h[d] - m) * inv * g[d] + bb[d];
        }

        // MLP: hidden j computed as scalar, immediately consumed (no big register array)
        {
            const float* W1 = mlp_w1 + li * HID * DM;
            const float* B1 = mlp_b1 + li * HID;
            const float* W2 = mlp_w2 + li * DM * HID;
            const float* B2 = mlp_b2 + li * DM;
            float acc2[DM];
            #pragma unroll
            for (int d = 0; d < DM; ++d) acc2[d] = B2[d];
            #pragma unroll 2
            for (int j = 0; j < HID; ++j) {
                float t = B1[j];
                #pragma unroll
                for (int d = 0; d < DM; ++d) t += xn2[d] * W1[j * DM + d];
                float g = 0.5f * t * (1.0f + erff(t * 0.70710678118654752f));
                #pragma unroll
                for (int d = 0; d < DM; ++d) acc2[d] += g * W2[d * HID + j];
            }
            #pragma unroll
            for (int d = 0; d < DM; ++d) h[d] += acc2[d];
        }
    }

    // ---- final LN (in place) ----
    {
        float m = 0.f;
        #pragma unroll
        for (int d = 0; d < DM; ++d) m += h[d];
        m *= (1.0f / DM);
        float v = 0.f;
        #pragma unroll
        for (int d = 0; d < DM; ++d) { float t = h[d] - m; v += t * t; }
        v *= (1.0f / DM);
        float inv = rsqrtf(v + EPSF);
        #pragma unroll
        for (int d = 0; d < DM; ++d) h[d] = (h[d] - m) * inv * lnf_g[d] + lnf_b[d];
    }

    if (valid) {
        // z output: (B, 16, 18), z[b,d,s] = h_final[s,d]
        float* zb = out_z + b * (DM * SEQ);
        #pragma unroll
        for (int d = 0; d < DM; ++d) zb[d * SEQ + s] = h[d];

        // decoder: stride==kernel==16 -> each t maps to exactly one (p=s, k): t = s*16 + k - 7
        float* yb = out_y + b * LIN;
        const float db0 = dec_b[0];
        #pragma unroll
        for (int k = 0; k < 16; ++k) {
            int t = s * 16 + k - 7;
            if (t >= 0 && t < LIN) {
                float acc = db0;
                #pragma unroll
                for (int d = 0; d < DM; ++d) acc += h[d] * dec_w[d * 16 + k];
                yb[t] = acc;
            }
        }
    }
}

extern "C" void kernel_launch(void* const* d_in, const int* in_sizes, int n_in,
                              void* d_out, int out_size, void* d_ws, size_t ws_size,
                              hipStream_t stream) {
    const float* x        = (const float*)d_in[0];
    const float* patch_w  = (const float*)d_in[1];
    const float* patch_b  = (const float*)d_in[2];
    const float* pos_e    = (const float*)d_in[3];
    const float* ln1_g    = (const float*)d_in[4];
    const float* ln1_b    = (const float*)d_in[5];
    const float* qkv_w    = (const float*)d_in[6];
    const float* qkv_b    = (const float*)d_in[7];
    const float* out_w    = (const float*)d_in[8];
    const float* out_b    = (const float*)d_in[9];
    const float* ln2_g    = (const float*)d_in[10];
    const float* ln2_b    = (const float*)d_in[11];
    const float* mlp_w1   = (const float*)d_in[12];
    const float* mlp_b1   = (const float*)d_in[13];
    const float* mlp_w2   = (const float*)d_in[14];
    const float* mlp_b2   = (const float*)d_in[15];
    const float* lnf_g    = (const float*)d_in[16];
    const float* lnf_b    = (const float*)d_in[17];
    const float* dec_w    = (const float*)d_in[18];
    const float* dec_b    = (const float*)d_in[19];

    float* out_y = (float*)d_out;                       // (B,1,274) first
    float* out_z = out_y + (long long)NB * LIN;         // then (B,16,18)

    const int grid = (NB + EPB - 1) / EPB;              // 4682
    ae_fwd<<<grid, NTHREADS, 0, stream>>>(
        x, patch_w, patch_b, pos_e, ln1_g, ln1_b, qkv_w, qkv_b,
        out_w, out_b, ln2_g, ln2_b, mlp_w1, mlp_b1, mlp_w2, mlp_b2,
        lnf_g, lnf_b, dec_w, dec_b, out_y, out_z);
}

// Round 2
// 933.548 us; speedup vs baseline: 1.2038x; 1.2038x over previous
//
#include <hip/hip_runtime.h>
#include <math.h>

#define NB      65536
#define LIN     274
#define SEQ     18
#define DM      16
#define NH      4
#define HID     64
#define NLAYER  4
#define EPSF    1e-5f

#define EPB      14              // elements (batch items) per block
#define NTHREADS (EPB * SEQ)     // 252 threads
#define KV_STRIDE 580            // floats per element in kv LDS (2*288 padded; 580%32=4 -> bank-spread, 16B aligned)

// fast approx helpers (1-ulp-ish HW ops; error budget: absmax threshold 7.1e-2, fp32-exact run used 1.6e-2)
__device__ __forceinline__ float fast_rcp(float x)  { return __builtin_amdgcn_rcpf(x); }
__device__ __forceinline__ float fast_rsq(float x)  { return __builtin_amdgcn_rsqf(x); }
__device__ __forceinline__ float fast_exp2(float x) { return __builtin_amdgcn_exp2f(x); }

// tanh-gelu, branch-free, 7 VALU ops, overflow-safe:
//   u = sqrt(2/pi)*(t + 0.044715 t^3);  gelu = t * e2u/(1+e2u) = t - t*rcp(1+e2u)
//   e2u=inf -> rcp=0 -> gelu=t ;  e2u=0 -> gelu=0
__device__ __forceinline__ float gelu_tanh(float t) {
    const float A = 0.79788456080286536f;           // sqrt(2/pi)
    const float B = 0.03567740814183430f;           // A*0.044715
    float t2 = t * t;
    float u  = t * fmaf(t2, B, A);
    float e  = fast_exp2(u * 2.88539008177792681f); // e^{2u} = 2^{2u*log2(e)}
    float r  = fast_rcp(e + 1.0f);
    return fmaf(-t, r, t);
}

__global__ __launch_bounds__(NTHREADS) void ae_fwd(
    const float* __restrict__ x,
    const float* __restrict__ patch_w, const float* __restrict__ patch_b,
    const float* __restrict__ pos_embed,
    const float* __restrict__ ln1_g, const float* __restrict__ ln1_b,
    const float* __restrict__ qkv_w, const float* __restrict__ qkv_b,
    const float* __restrict__ out_w, const float* __restrict__ out_b,
    const float* __restrict__ ln2_g, const float* __restrict__ ln2_b,
    const float* __restrict__ mlp_w1, const float* __restrict__ mlp_b1,
    const float* __restrict__ mlp_w2, const float* __restrict__ mlp_b2,
    const float* __restrict__ lnf_g, const float* __restrict__ lnf_b,
    const float* __restrict__ dec_w, const float* __restrict__ dec_b,
    float* __restrict__ out_y, float* __restrict__ out_z)
{
    __shared__ float s_kv[EPB * KV_STRIDE];   // 32480 B; aliased as x-staging first

    const int tid = threadIdx.x;
    const int e   = tid / SEQ;
    const int s   = tid - e * SEQ;
    const long long b = (long long)blockIdx.x * EPB + e;
    const bool valid = (b < NB);

    // ---- stage x into LDS, fully coalesced ----
    {
        const long long base = (long long)blockIdx.x * (EPB * LIN);
        const long long lim  = (long long)NB * LIN - 1;
        for (int i = tid; i < EPB * LIN; i += NTHREADS) {
            long long gi = base + i;
            if (gi > lim) gi = lim;               // tail-block clamp (no OOB)
            s_kv[i] = x[gi];
        }
    }
    __syncthreads();

    // ---- patchify ----
    float xv[16];
    {
        const float* xe = &s_kv[e * LIN];
        #pragma unroll
        for (int k = 0; k < 16; ++k) {
            int idx = s * 16 - 7 + k;
            xv[k] = (idx >= 0 && idx < LIN) ? xe[idx] : 0.0f;
        }
    }
    float h[DM];
    #pragma unroll
    for (int d = 0; d < DM; ++d) {
        float acc = patch_b[d] + pos_embed[s * DM + d];
        #pragma unroll
        for (int k = 0; k < 16; ++k) acc = fmaf(xv[k], patch_w[d * 16 + k], acc);
        h[d] = acc;
    }

    // ---- transformer layers ----
    #pragma unroll 1
    for (int li = 0; li < NLAYER; ++li) {
        // LN1
        float xn[DM];
        {
            float m = 0.f;
            #pragma unroll
            for (int d = 0; d < DM; ++d) m += h[d];
            m *= (1.0f / DM);
            float v = 0.f;
            #pragma unroll
            for (int d = 0; d < DM; ++d) { float t = h[d] - m; v = fmaf(t, t, v); }
            v *= (1.0f / DM);
            float inv = fast_rsq(v + EPSF);
            const float* g = ln1_g + li * DM;
            const float* bb = ln1_b + li * DM;
            #pragma unroll
            for (int d = 0; d < DM; ++d) xn[d] = (h[d] - m) * inv * g[d] + bb[d];
        }

        // qkv
        float q[DM], kk[DM], vv[DM];
        {
            const float* W  = qkv_w + li * (3 * DM) * DM;
            const float* Wb = qkv_b + li * (3 * DM);
            #pragma unroll
            for (int j = 0; j < DM; ++j) {
                float aq = Wb[j], ak = Wb[DM + j], av = Wb[2 * DM + j];
                #pragma unroll
                for (int d = 0; d < DM; ++d) {
                    float xd = xn[d];
                    aq = fmaf(xd, W[(j) * DM + d], aq);
                    ak = fmaf(xd, W[(DM + j) * DM + d], ak);
                    av = fmaf(xd, W[(2 * DM + j) * DM + d], av);
                }
                q[j] = aq; kk[j] = ak; vv[j] = av;
            }
        }

        // publish k,v rows to LDS
        __syncthreads();
        {
            float* kb = &s_kv[e * KV_STRIDE];
            float* vb = kb + SEQ * DM;
            #pragma unroll
            for (int j = 0; j < DM; ++j) kb[s * DM + j] = kk[j];
            #pragma unroll
            for (int j = 0; j < DM; ++j) vb[s * DM + j] = vv[j];
        }
        __syncthreads();

        // attention. Scale folded into q: 1/sqrt(DH) * log2(e) so scores feed exp2 directly.
        // No max-subtraction: scores ~ N(0, ~0.65^2); exp2 overflow would need score*1.4427 > 128 (~135 sigma).
        float o[DM];
        {
            const float* kb = &s_kv[e * KV_STRIDE];
            const float* vb = kb + SEQ * DM;
            #pragma unroll
            for (int hh = 0; hh < NH; ++hh) {
                const float qscale = 0.5f * 1.44269504088896341f;  // (1/sqrt(4)) * log2(e)
                const float q0 = q[hh * 4] * qscale, q1 = q[hh * 4 + 1] * qscale;
                const float q2 = q[hh * 4 + 2] * qscale, q3 = q[hh * 4 + 3] * qscale;
                float sc[SEQ];
                float ssum = 0.f;
                #pragma unroll
                for (int j = 0; j < SEQ; ++j) {
                    const float4 kj = *(const float4*)(kb + j * DM + hh * 4);
                    float t = fmaf(q0, kj.x, fmaf(q1, kj.y, fmaf(q2, kj.z, q3 * kj.w)));
                    float w = fast_exp2(t);
                    sc[j] = w;
                    ssum += w;
                }
                const float inv = fast_rcp(ssum);
                float a0 = 0.f, a1 = 0.f, a2 = 0.f, a3 = 0.f;
                #pragma unroll
                for (int j = 0; j < SEQ; ++j) {
                    const float4 vj = *(const float4*)(vb + j * DM + hh * 4);
                    const float w = sc[j] * inv;
                    a0 = fmaf(w, vj.x, a0); a1 = fmaf(w, vj.y, a1);
                    a2 = fmaf(w, vj.z, a2); a3 = fmaf(w, vj.w, a3);
                }
                o[hh * 4] = a0; o[hh * 4 + 1] = a1; o[hh * 4 + 2] = a2; o[hh * 4 + 3] = a3;
            }
        }

        // out projection + residual
        {
            const float* W  = out_w + li * DM * DM;
            const float* Wb = out_b + li * DM;
            #pragma unroll
            for (int d = 0; d < DM; ++d) {
                float acc = Wb[d];
                #pragma unroll
                for (int d2 = 0; d2 < DM; ++d2) acc = fmaf(o[d2], W[d * DM + d2], acc);
                h[d] += acc;
            }
        }

        // LN2
        float xn2[DM];
        {
            float m = 0.f;
            #pragma unroll
            for (int d = 0; d < DM; ++d) m += h[d];
            m *= (1.0f / DM);
            float v = 0.f;
            #pragma unroll
            for (int d = 0; d < DM; ++d) { float t = h[d] - m; v = fmaf(t, t, v); }
            v *= (1.0f / DM);
            float inv = fast_rsq(v + EPSF);
            const float* g = ln2_g + li * DM;
            const float* bb = ln2_b + li * DM;
            #pragma unroll
            for (int d = 0; d < DM; ++d) xn2[d] = (h[d] - m) * inv * g[d] + bb[d];
        }

        // MLP with cheap gelu
        {
            const float* W1 = mlp_w1 + li * HID * DM;
            const float* B1 = mlp_b1 + li * HID;
            const float* W2 = mlp_w2 + li * DM * HID;
            const float* B2 = mlp_b2 + li * DM;
            float acc2[DM];
            #pragma unroll
            for (int d = 0; d < DM; ++d) acc2[d] = B2[d];
            #pragma unroll 2
            for (int j = 0; j < HID; ++j) {
                float t = B1[j];
                #pragma unroll
                for (int d = 0; d < DM; ++d) t = fmaf(xn2[d], W1[j * DM + d], t);
                float g = gelu_tanh(t);
                #pragma unroll
                for (int d = 0; d < DM; ++d) acc2[d] = fmaf(g, W2[d * HID + j], acc2[d]);
            }
            #pragma unroll
            for (int d = 0; d < DM; ++d) h[d] += acc2[d];
        }
    }

    // ---- final LN ----
    {
        float m = 0.f;
        #pragma unroll
        for (int d = 0; d < DM; ++d) m += h[d];
        m *= (1.0f / DM);
        float v = 0.f;
        #pragma unroll
        for (int d = 0; d < DM; ++d) { float t = h[d] - m; v = fmaf(t, t, v); }
        v *= (1.0f / DM);
        float inv = fast_rsq(v + EPSF);
        #pragma unroll
        for (int d = 0; d < DM; ++d) h[d] = (h[d] - m) * inv * lnf_g[d] + lnf_b[d];
    }

    if (valid) {
        // z output: (B, 16, 18)
        float* zb = out_z + b * (DM * SEQ);
        #pragma unroll
        for (int d = 0; d < DM; ++d) zb[d * SEQ + s] = h[d];

        // decoder
        float* yb = out_y + b * LIN;
        const float db0 = dec_b[0];
        #pragma unroll
        for (int k = 0; k < 16; ++k) {
            int t = s * 16 + k - 7;
            if (t >= 0 && t < LIN) {
                float acc = db0;
                #pragma unroll
                for (int d = 0; d < DM; ++d) acc = fmaf(h[d], dec_w[d * 16 + k], acc);
                yb[t] = acc;
            }
        }
    }
}

extern "C" void kernel_launch(void* const* d_in, const int* in_sizes, int n_in,
                              void* d_out, int out_size, void* d_ws, size_t ws_size,
                              hipStream_t stream) {
    const float* x        = (const float*)d_in[0];
    const float* patch_w  = (const float*)d_in[1];
    const float* patch_b  = (const float*)d_in[2];
    const float* pos_e    = (const float*)d_in[3];
    const float* ln1_g    = (const float*)d_in[4];
    const float* ln1_b    = (const float*)d_in[5];
    const float* qkv_w    = (const float*)d_in[6];
    const float* qkv_b    = (const float*)d_in[7];
    const float* out_w    = (const float*)d_in[8];
    const float* out_b    = (const float*)d_in[9];
    const float* ln2_g    = (const float*)d_in[10];
    const float* ln2_b    = (const float*)d_in[11];
    const float* mlp_w1   = (const float*)d_in[12];
    const float* mlp_b1   = (const float*)d_in[13];
    const float* mlp_w2   = (const float*)d_in[14];
    const float* mlp_b2   = (const float*)d_in[15];
    const float* lnf_g    = (const float*)d_in[16];
    const float* lnf_b    = (const float*)d_in[17];
    const float* dec_w    = (const float*)d_in[18];
    const float* dec_b    = (const float*)d_in[19];

    float* out_y = (float*)d_out;                       // (B,1,274) first
    float* out_z = out_y + (long long)NB * LIN;         // then (B,16,18)

    const int grid = (NB + EPB - 1) / EPB;              // 4682
    ae_fwd<<<grid, NTHREADS, 0, stream>>>(
        x, patch_w, patch_b, pos_e, ln1_g, ln1_b, qkv_w, qkv_b,
        out_w, out_b, ln2_g, ln2_b, mlp_w1, mlp_b1, mlp_w2, mlp_b2,
        lnf_g, lnf_b, dec_w, dec_b, out_y, out_z);
}

// Round 4
// 704.670 us; speedup vs baseline: 1.5948x; 1.3248x over previous
//
#include <hip/hip_runtime.h>
#include <math.h>
#include <stdint.h>

#define NB      65536
#define LIN     274
#define SEQ     18
#define DM      16
#define NH      4
#define HID     64
#define NLAYER  4
#define EPSF    1e-5f

#define EPB      14              // elements per block
#define NTHREADS (EPB * SEQ)     // 252 threads
// per-element LDS: K as h2 pairs = 144 dwords, V fp32 = 288 dwords, pad -> 436
// 436 % 32 = 20 -> element bank spacing {0,20,8,28}: disjoint for b64/b128 reads
#define ESTRIDE  436
#define VOFF     144

typedef _Float16 h2 __attribute__((ext_vector_type(2)));
typedef __fp16   hf2_raw __attribute__((ext_vector_type(2)));

#if __has_builtin(__builtin_amdgcn_fdot2)
__device__ __forceinline__ float fdot2(h2 a, h2 b, float c) { return __builtin_amdgcn_fdot2(a, b, c, false); }
#else
__device__ __forceinline__ float fdot2(h2 a, h2 b, float c) { return c + (float)a[0] * (float)b[0] + (float)a[1] * (float)b[1]; }
#endif
#if __has_builtin(__builtin_amdgcn_cvt_pkrtz)
__device__ __forceinline__ h2 pkrtz(float a, float b) {
    hf2_raw r = __builtin_amdgcn_cvt_pkrtz(a, b);
    return __builtin_bit_cast(h2, r);
}
#else
__device__ __forceinline__ h2 pkrtz(float a, float b) { h2 r; r[0] = (_Float16)a; r[1] = (_Float16)b; return r; }
#endif

__device__ __forceinline__ float fast_rcp(float x)  { return __builtin_amdgcn_rcpf(x); }
__device__ __forceinline__ float fast_rsq(float x)  { return __builtin_amdgcn_rsqf(x); }
__device__ __forceinline__ float fast_exp2(float x) { return __builtin_amdgcn_exp2f(x); }

__device__ __forceinline__ float gelu_tanh(float t) {
    const float A = 0.79788456080286536f;           // sqrt(2/pi)
    const float B = 0.03567740814183430f;           // A*0.044715
    float t2 = t * t;
    float u  = t * fmaf(t2, B, A);
    float e  = fast_exp2(u * 2.88539008177792681f); // e^{2u}
    float r  = fast_rcp(e + 1.0f);
    return fmaf(-t, r, t);
}

// ---- weight packing layout in d_ws (h2 units) ----
// QKV : [0,1536)       idx = li*384 + j*8 + p      pairs over d of qkv_w[li][j][d]
// OUT : [1536,2048)    idx = 1536 + li*128 + d*8+p pairs over d2 of out_w[li][d][d2]
// W1  : [2048,4096)    idx = 2048 + li*512 + j*8+p pairs over d of mlp_w1[li][j][d]
// W2  : [4096,6144)    idx = 4096 + li*512 + c*128 + d*8 + p  pairs (j=c*16+2p,+1) of mlp_w2[li][d][j]
#define WS_H2_COUNT 6144

__global__ __launch_bounds__(512) void prep_weights(
    const float* __restrict__ qkv_w, const float* __restrict__ out_w,
    const float* __restrict__ mlp_w1, const float* __restrict__ mlp_w2,
    h2* __restrict__ ws)
{
    int i = blockIdx.x * 512 + threadIdx.x;
    if (i >= WS_H2_COUNT) return;
    float a, b;
    if (i < 1536) {
        int li = i / 384, r = i % 384, j = r / 8, p = r % 8;
        const float* s = qkv_w + li * 768 + j * 16 + 2 * p; a = s[0]; b = s[1];
    } else if (i < 2048) {
        int t = i - 1536, li = t / 128, r = t % 128, d = r / 8, p = r % 8;
        const float* s = out_w + li * 256 + d * 16 + 2 * p; a = s[0]; b = s[1];
    } else if (i < 4096) {
        int t = i - 2048, li = t / 512, r = t % 512, j = r / 8, p = r % 8;
        const float* s = mlp_w1 + li * 1024 + j * 16 + 2 * p; a = s[0]; b = s[1];
    } else {
        int t = i - 4096, li = t / 512, r = t % 512, c = r / 128, r2 = r % 128, d = r2 / 8, p = r2 % 8;
        const float* s = mlp_w2 + li * 1024 + d * 64 + c * 16 + 2 * p; a = s[0]; b = s[1];
    }
    ws[i] = pkrtz(a, b);
}

__global__ __launch_bounds__(NTHREADS) void ae_fwd(
    const float* __restrict__ x,
    const float* __restrict__ patch_w, const float* __restrict__ patch_b,
    const float* __restrict__ pos_embed,
    const float* __restrict__ ln1_g, const float* __restrict__ ln1_b,
    const h2*    __restrict__ wp,
    const float* __restrict__ qkv_b, const float* __restrict__ out_b,
    const float* __restrict__ ln2_g, const float* __restrict__ ln2_b,
    const float* __restrict__ mlp_b1, const float* __restrict__ mlp_b2,
    const float* __restrict__ lnf_g, const float* __restrict__ lnf_b,
    const float* __restrict__ dec_w, const float* __restrict__ dec_b,
    float* __restrict__ out_y, float* __restrict__ out_z)
{
    __shared__ float s_kv[EPB * ESTRIDE];   // 24416 B; first 3836 floats alias x-staging

    const int tid = threadIdx.x;
    const int e   = tid / SEQ;
    const int s   = tid - e * SEQ;
    const long long b = (long long)blockIdx.x * EPB + e;
    const bool valid = (b < NB);

    // ---- stage x into LDS, coalesced ----
    {
        const long long base = (long long)blockIdx.x * (EPB * LIN);
        const long long lim  = (long long)NB * LIN - 1;
        for (int i = tid; i < EPB * LIN; i += NTHREADS) {
            long long gi = base + i;
            if (gi > lim) gi = lim;
            s_kv[i] = x[gi];
        }
    }
    __syncthreads();

    // ---- patchify (fp32) ----
    float xv[16];
    {
        const float* xe = &s_kv[e * LIN];
        #pragma unroll
        for (int k = 0; k < 16; ++k) {
            int idx = s * 16 - 7 + k;
            xv[k] = (idx >= 0 && idx < LIN) ? xe[idx] : 0.0f;
        }
    }
    float h[DM];
    #pragma unroll
    for (int d = 0; d < DM; ++d) {
        float acc = patch_b[d] + pos_embed[s * DM + d];
        #pragma unroll
        for (int k = 0; k < 16; ++k) acc = fmaf(xv[k], patch_w[d * 16 + k], acc);
        h[d] = acc;
    }

    // ---- transformer layers ----
    #pragma unroll 1
    for (int li = 0; li < NLAYER; ++li) {
        // LN1 -> packed f16 activation
        h2 xp[8];
        {
            float m = 0.f;
            #pragma unroll
            for (int d = 0; d < DM; ++d) m += h[d];
            m *= (1.0f / DM);
            float v = 0.f;
            #pragma unroll
            for (int d = 0; d < DM; ++d) { float t = h[d] - m; v = fmaf(t, t, v); }
            v *= (1.0f / DM);
            float inv = fast_rsq(v + EPSF);
            const float* g = ln1_g + li * DM;
            const float* bb = ln1_b + li * DM;
            float xn[DM];
            #pragma unroll
            for (int d = 0; d < DM; ++d) xn[d] = (h[d] - m) * inv * g[d] + bb[d];
            #pragma unroll
            for (int i = 0; i < 8; ++i) xp[i] = pkrtz(xn[2 * i], xn[2 * i + 1]);
        }

        // qkv via dot2 (weights: uniform scalar loads)
        float q[DM], kk[DM], vv[DM];
        {
            const h2* Wl = wp + li * 384;
            const float* Wb = qkv_b + li * 48;
            #pragma unroll
            for (int j = 0; j < DM; ++j) {
                float aq = Wb[j], ak = Wb[16 + j], av = Wb[32 + j];
                const h2* wq = Wl + j * 8;
                const h2* wk = Wl + (16 + j) * 8;
                const h2* wv = Wl + (32 + j) * 8;
                #pragma unroll
                for (int i = 0; i < 8; ++i) {
                    aq = fdot2(xp[i], wq[i], aq);
                    ak = fdot2(xp[i], wk[i], ak);
                    av = fdot2(xp[i], wv[i], av);
                }
                q[j] = aq; kk[j] = ak; vv[j] = av;
            }
        }

        // publish K (f16 pairs) and V (fp32) to LDS
        __syncthreads();
        {
            h2* kW = (h2*)&s_kv[e * ESTRIDE];
            float* vW = &s_kv[e * ESTRIDE + VOFF];
            #pragma unroll
            for (int i = 0; i < 8; ++i) kW[s * 8 + i] = pkrtz(kk[2 * i], kk[2 * i + 1]);
            #pragma unroll
            for (int j = 0; j < DM; ++j) vW[s * 16 + j] = vv[j];
        }
        __syncthreads();

        // attention: scores via f16 dot2, exp2 direct (scale+log2e folded into q)
        float o[DM];
        {
            const h2* kK = (const h2*)&s_kv[e * ESTRIDE];
            const float* vb = &s_kv[e * ESTRIDE + VOFF];
            const float qs = 0.5f * 1.44269504088896341f;
            #pragma unroll
            for (int hh = 0; hh < NH; ++hh) {
                h2 qp0 = pkrtz(q[4 * hh] * qs, q[4 * hh + 1] * qs);
                h2 qp1 = pkrtz(q[4 * hh + 2] * qs, q[4 * hh + 3] * qs);
                float sc[SEQ];
                float ssum = 0.f;
                #pragma unroll
                for (int j = 0; j < SEQ; ++j) {
                    float t = fdot2(qp1, kK[j * 8 + hh * 2 + 1], fdot2(qp0, kK[j * 8 + hh * 2], 0.0f));
                    float w = fast_exp2(t);
                    sc[j] = w; ssum += w;
                }
                const float inv = fast_rcp(ssum);
                float a0 = 0.f, a1 = 0.f, a2 = 0.f, a3 = 0.f;
                #pragma unroll
                for (int j = 0; j < SEQ; ++j) {
                    const float4 vj = *(const float4*)(vb + j * 16 + hh * 4);
                    const float w = sc[j] * inv;
                    a0 = fmaf(w, vj.x, a0); a1 = fmaf(w, vj.y, a1);
                    a2 = fmaf(w, vj.z, a2); a3 = fmaf(w, vj.w, a3);
                }
                o[hh * 4] = a0; o[hh * 4 + 1] = a1; o[hh * 4 + 2] = a2; o[hh * 4 + 3] = a3;
            }
        }

        // out projection via dot2 + residual
        {
            h2 op[8];
            #pragma unroll
            for (int i = 0; i < 8; ++i) op[i] = pkrtz(o[2 * i], o[2 * i + 1]);
            const h2* Wl = wp + 1536 + li * 128;
            const float* Wb = out_b + li * DM;
            #pragma unroll
            for (int d = 0; d < DM; ++d) {
                float acc = Wb[d];
                const h2* w = Wl + d * 8;
                #pragma unroll
                for (int i = 0; i < 8; ++i) acc = fdot2(op[i], w[i], acc);
                h[d] += acc;
            }
        }

        // LN2 -> packed
        h2 xp2[8];
        {
            float m = 0.f;
            #pragma unroll
            for (int d = 0; d < DM; ++d) m += h[d];
            m *= (1.0f / DM);
            float v = 0.f;
            #pragma unroll
            for (int d = 0; d < DM; ++d) { float t = h[d] - m; v = fmaf(t, t, v); }
            v *= (1.0f / DM);
            float inv = fast_rsq(v + EPSF);
            const float* g = ln2_g + li * DM;
            const float* bb = ln2_b + li * DM;
            float xn2[DM];
            #pragma unroll
            for (int d = 0; d < DM; ++d) xn2[d] = (h[d] - m) * inv * g[d] + bb[d];
            #pragma unroll
            for (int i = 0; i < 8; ++i) xp2[i] = pkrtz(xn2[2 * i], xn2[2 * i + 1]);
        }

        // MLP in 4 chunks of 16 hidden units, both matmuls via dot2
        {
            const h2* W1l = wp + 2048 + li * 512;
            const h2* W2l = wp + 4096 + li * 512;
            const float* B1 = mlp_b1 + li * HID;
            const float* B2 = mlp_b2 + li * DM;
            float acc2[DM];
            #pragma unroll
            for (int d = 0; d < DM; ++d) acc2[d] = B2[d];
            for (int c = 0; c < 4; ++c) {
                float g[16];
                #pragma unroll
                for (int j = 0; j < 16; ++j) {
                    float t = B1[c * 16 + j];
                    const h2* w = W1l + (c * 16 + j) * 8;
                    #pragma unroll
                    for (int i = 0; i < 8; ++i) t = fdot2(xp2[i], w[i], t);
                    g[j] = gelu_tanh(t);
                }
                h2 gp[8];
                #pragma unroll
                for (int i = 0; i < 8; ++i) gp[i] = pkrtz(g[2 * i], g[2 * i + 1]);
                #pragma unroll
                for (int d = 0; d < DM; ++d) {
                    float t = acc2[d];
                    const h2* w = W2l + c * 128 + d * 8;
                    #pragma unroll
                    for (int i = 0; i < 8; ++i) t = fdot2(gp[i], w[i], t);
                    acc2[d] = t;
                }
            }
            #pragma unroll
            for (int d = 0; d < DM; ++d) h[d] += acc2[d];
        }
    }

    // ---- final LN (fp32) ----
    {
        float m = 0.f;
        #pragma unroll
        for (int d = 0; d < DM; ++d) m += h[d];
        m *= (1.0f / DM);
        float v = 0.f;
        #pragma unroll
        for (int d = 0; d < DM; ++d) { float t = h[d] - m; v = fmaf(t, t, v); }
        v *= (1.0f / DM);
        float inv = fast_rsq(v + EPSF);
        #pragma unroll
        for (int d = 0; d < DM; ++d) h[d] = (h[d] - m) * inv * lnf_g[d] + lnf_b[d];
    }

    if (valid) {
        float* zb = out_z + b * (DM * SEQ);
        #pragma unroll
        for (int d = 0; d < DM; ++d) zb[d * SEQ + s] = h[d];

        float* yb = out_y + b * LIN;
        const float db0 = dec_b[0];
        #pragma unroll
        for (int k = 0; k < 16; ++k) {
            int t = s * 16 + k - 7;
            if (t >= 0 && t < LIN) {
                float acc = db0;
                #pragma unroll
                for (int d = 0; d < DM; ++d) acc = fmaf(h[d], dec_w[d * 16 + k], acc);
                yb[t] = acc;
            }
        }
    }
}

// ---------------- fp32 fallback (used only if ws_size is too small) ----------------
__global__ __launch_bounds__(NTHREADS) void ae_fwd_f32(
    const float* __restrict__ x,
    const float* __restrict__ patch_w, const float* __restrict__ patch_b,
    const float* __restrict__ pos_embed,
    const float* __restrict__ ln1_g, const float* __restrict__ ln1_b,
    const float* __restrict__ qkv_w, const float* __restrict__ qkv_b,
    const float* __restrict__ out_w, const float* __restrict__ out_b,
    const float* __restrict__ ln2_g, const float* __restrict__ ln2_b,
    const float* __restrict__ mlp_w1, const float* __restrict__ mlp_b1,
    const float* __restrict__ mlp_w2, const float* __restrict__ mlp_b2,
    const float* __restrict__ lnf_g, const float* __restrict__ lnf_b,
    const float* __restrict__ dec_w, const float* __restrict__ dec_b,
    float* __restrict__ out_y, float* __restrict__ out_z)
{
    __shared__ float s_kv[EPB * 580];
    const int tid = threadIdx.x;
    const int e   = tid / SEQ;
    const int s   = tid - e * SEQ;
    const long long b = (long long)blockIdx.x * EPB + e;
    const bool valid = (b < NB);
    {
        const long long base = (long long)blockIdx.x * (EPB * LIN);
        const long long lim  = (long long)NB * LIN - 1;
        for (int i = tid; i < EPB * LIN; i += NTHREADS) {
            long long gi = base + i;
            if (gi > lim) gi = lim;
            s_kv[i] = x[gi];
        }
    }
    __syncthreads();
    float xv[16];
    {
        const float* xe = &s_kv[e * LIN];
        #pragma unroll
        for (int k = 0; k < 16; ++k) {
            int idx = s * 16 - 7 + k;
            xv[k] = (idx >= 0 && idx < LIN) ? xe[idx] : 0.0f;
        }
    }
    float h[DM];
    #pragma unroll
    for (int d = 0; d < DM; ++d) {
        float acc = patch_b[d] + pos_embed[s * DM + d];
        #pragma unroll
        for (int k = 0; k < 16; ++k) acc = fmaf(xv[k], patch_w[d * 16 + k], acc);
        h[d] = acc;
    }
    #pragma unroll 1
    for (int li = 0; li < NLAYER; ++li) {
        float xn[DM];
        {
            float m = 0.f;
            #pragma unroll
            for (int d = 0; d < DM; ++d) m += h[d];
            m *= (1.0f / DM);
            float v = 0.f;
            #pragma unroll
            for (int d = 0; d < DM; ++d) { float t = h[d] - m; v = fmaf(t, t, v); }
            v *= (1.0f / DM);
            float inv = fast_rsq(v + EPSF);
            #pragma unroll
            for (int d = 0; d < DM; ++d) xn[d] = (h[d] - m) * inv * ln1_g[li * DM + d] + ln1_b[li * DM + d];
        }
        float q[DM], kk[DM], vv[DM];
        {
            const float* W  = qkv_w + li * 48 * DM;
            const float* Wb = qkv_b + li * 48;
            #pragma unroll
            for (int j = 0; j < DM; ++j) {
                float aq = Wb[j], ak = Wb[DM + j], av = Wb[2 * DM + j];
                #pragma unroll
                for (int d = 0; d < DM; ++d) {
                    float xd = xn[d];
                    aq = fmaf(xd, W[j * DM + d], aq);
                    ak = fmaf(xd, W[(DM + j) * DM + d], ak);
                    av = fmaf(xd, W[(2 * DM + j) * DM + d], av);
                }
                q[j] = aq; kk[j] = ak; vv[j] = av;
            }
        }
        __syncthreads();
        {
            float* kb = &s_kv[e * 580];
            float* vb = kb + SEQ * DM;
            #pragma unroll
            for (int j = 0; j < DM; ++j) kb[s * DM + j] = kk[j];
            #pragma unroll
            for (int j = 0; j < DM; ++j) vb[s * DM + j] = vv[j];
        }
        __syncthreads();
        float o[DM];
        {
            const float* kb = &s_kv[e * 580];
            const float* vb = kb + SEQ * DM;
            #pragma unroll
            for (int hh = 0; hh < NH; ++hh) {
                const float qscale = 0.5f * 1.44269504088896341f;
                const float q0 = q[hh * 4] * qscale, q1 = q[hh * 4 + 1] * qscale;
                const float q2 = q[hh * 4 + 2] * qscale, q3 = q[hh * 4 + 3] * qscale;
                float sc[SEQ];
                float ssum = 0.f;
                #pragma unroll
                for (int j = 0; j < SEQ; ++j) {
                    const float4 kj = *(const float4*)(kb + j * DM + hh * 4);
                    float t = fmaf(q0, kj.x, fmaf(q1, kj.y, fmaf(q2, kj.z, q3 * kj.w)));
                    float w = fast_exp2(t);
                    sc[j] = w; ssum += w;
                }
                const float inv = fast_rcp(ssum);
                float a0 = 0.f, a1 = 0.f, a2 = 0.f, a3 = 0.f;
                #pragma unroll
                for (int j = 0; j < SEQ; ++j) {
                    const float4 vj = *(const float4*)(vb + j * DM + hh * 4);
                    const float w = sc[j] * inv;
                    a0 = fmaf(w, vj.x, a0); a1 = fmaf(w, vj.y, a1);
                    a2 = fmaf(w, vj.z, a2); a3 = fmaf(w, vj.w, a3);
                }
                o[hh * 4] = a0; o[hh * 4 + 1] = a1; o[hh * 4 + 2] = a2; o[hh * 4 + 3] = a3;
            }
        }
        {
            const float* W  = out_w + li * DM * DM;
            #pragma unroll
            for (int d = 0; d < DM; ++d) {
                float acc = out_b[li * DM + d];
                #pragma unroll
                for (int d2 = 0; d2 < DM; ++d2) acc = fmaf(o[d2], W[d * DM + d2], acc);
                h[d] += acc;
            }
        }
        float xn2[DM];
        {
            float m = 0.f;
            #pragma unroll
            for (int d = 0; d < DM; ++d) m += h[d];
            m *= (1.0f / DM);
            float v = 0.f;
            #pragma unroll
            for (int d = 0; d < DM; ++d) { float t = h[d] - m; v = fmaf(t, t, v); }
            v *= (1.0f / DM);
            float inv = fast_rsq(v + EPSF);
            #pragma unroll
            for (int d = 0; d < DM; ++d) xn2[d] = (h[d] - m) * inv * ln2_g[li * DM + d] + ln2_b[li * DM + d];
        }
        {
            const float* W1 = mlp_w1 + li * HID * DM;
            const float* W2 = mlp_w2 + li * DM * HID;
            float acc2[DM];
            #pragma unroll
            for (int d = 0; d < DM; ++d) acc2[d] = mlp_b2[li * DM + d];
            #pragma unroll 2
            for (int j = 0; j < HID; ++j) {
                float t = mlp_b1[li * HID + j];
                #pragma unroll
                for (int d = 0; d < DM; ++d) t = fmaf(xn2[d], W1[j * DM + d], t);
                float g = gelu_tanh(t);
                #pragma unroll
                for (int d = 0; d < DM; ++d) acc2[d] = fmaf(g, W2[d * HID + j], acc2[d]);
            }
            #pragma unroll
            for (int d = 0; d < DM; ++d) h[d] += acc2[d];
        }
    }
    {
        float m = 0.f;
        #pragma unroll
        for (int d = 0; d < DM; ++d) m += h[d];
        m *= (1.0f / DM);
        float v = 0.f;
        #pragma unroll
        for (int d = 0; d < DM; ++d) { float t = h[d] - m; v = fmaf(t, t, v); }
        v *= (1.0f / DM);
        float inv = fast_rsq(v + EPSF);
        #pragma unroll
        for (int d = 0; d < DM; ++d) h[d] = (h[d] - m) * inv * lnf_g[d] + lnf_b[d];
    }
    if (valid) {
        float* zb = out_z + b * (DM * SEQ);
        #pragma unroll
        for (int d = 0; d < DM; ++d) zb[d * SEQ + s] = h[d];
        float* yb = out_y + b * LIN;
        const float db0 = dec_b[0];
        #pragma unroll
        for (int k = 0; k < 16; ++k) {
            int t = s * 16 + k - 7;
            if (t >= 0 && t < LIN) {
                float acc = db0;
                #pragma unroll
                for (int d = 0; d < DM; ++d) acc = fmaf(h[d], dec_w[d * 16 + k], acc);
                yb[t] = acc;
            }
        }
    }
}

extern "C" void kernel_launch(void* const* d_in, const int* in_sizes, int n_in,
                              void* d_out, int out_size, void* d_ws, size_t ws_size,
                              hipStream_t stream) {
    const float* x        = (const float*)d_in[0];
    const float* patch_w  = (const float*)d_in[1];
    const float* patch_b  = (const float*)d_in[2];
    const float* pos_e    = (const float*)d_in[3];
    const float* ln1_g    = (const float*)d_in[4];
    const float* ln1_b    = (const float*)d_in[5];
    const float* qkv_w    = (const float*)d_in[6];
    const float* qkv_b    = (const float*)d_in[7];
    const float* out_w    = (const float*)d_in[8];
    const float* out_b    = (const float*)d_in[9];
    const float* ln2_g    = (const float*)d_in[10];
    const float* ln2_b    = (const float*)d_in[11];
    const float* mlp_w1   = (const float*)d_in[12];
    const float* mlp_b1   = (const float*)d_in[13];
    const float* mlp_w2   = (const float*)d_in[14];
    const float* mlp_b2   = (const float*)d_in[15];
    const float* lnf_g    = (const float*)d_in[16];
    const float* lnf_b    = (const float*)d_in[17];
    const float* dec_w    = (const float*)d_in[18];
    const float* dec_b    = (const float*)d_in[19];

    float* out_y = (float*)d_out;                       // (B,1,274) first
    float* out_z = out_y + (long long)NB * LIN;         // then (B,16,18)

    const int grid = (NB + EPB - 1) / EPB;              // 4682

    if (ws_size >= WS_H2_COUNT * sizeof(h2)) {
        h2* wsp = (h2*)d_ws;
        prep_weights<<<(WS_H2_COUNT + 511) / 512, 512, 0, stream>>>(qkv_w, out_w, mlp_w1, mlp_w2, wsp);
        ae_fwd<<<grid, NTHREADS, 0, stream>>>(
            x, patch_w, patch_b, pos_e, ln1_g, ln1_b, wsp,
            qkv_b, out_b, ln2_g, ln2_b, mlp_b1, mlp_b2,
            lnf_g, lnf_b, dec_w, dec_b, out_y, out_z);
    } else {
        ae_fwd_f32<<<grid, NTHREADS, 0, stream>>>(
            x, patch_w, patch_b, pos_e, ln1_g, ln1_b, qkv_w, qkv_b,
            out_w, out_b, ln2_g, ln2_b, mlp_w1, mlp_b1, mlp_w2, mlp_b2,
            lnf_g, lnf_b, dec_w, dec_b, out_y, out_z);
    }
}